// Round 1
// baseline (303.582 us; speedup 1.0000x reference)
//
#include <hip/hip_runtime.h>

#define N_ROWS 4194304
#define RPT 4            // rows per thread (weight-load amortization + ILP)
#define BLOCK 256

__device__ __forceinline__ float rrelu(float v) {
    // RReLU eval mode == leaky relu, slope (0.001+0.004)/2 = 0.0025
    return v >= 0.0f ? v : 0.0025f * v;
}

struct Weights {
    const float *W_in,  *b_in,  *W_h1,  *b_h1,  *W_h2, *b_h2, *W_h3, *b_h3,
                *W_h4,  *b_h4,  *W_h5,  *b_h5,  *W_enc, *b_enc,
                *W_h6,  *b_h6,  *W_h7,  *b_h7,  *W_h8, *b_h8, *W_h9, *b_h9,
                *W_h10, *b_h10, *W_dec, *b_dec;
};

// x = x + lin(rrelu(lin(x, Wa, ba)), Wb, bb)   (all 4x4)
__device__ __forceinline__ void resblock(float x[RPT][4],
                                         const float* __restrict__ Wa,
                                         const float* __restrict__ ba,
                                         const float* __restrict__ Wb,
                                         const float* __restrict__ bb) {
    float t[RPT][4];
#pragma unroll
    for (int j = 0; j < 4; ++j) {
#pragma unroll
        for (int k = 0; k < RPT; ++k) {
            float acc = ba[j];
#pragma unroll
            for (int i = 0; i < 4; ++i) acc = fmaf(x[k][i], Wa[i * 4 + j], acc);
            t[k][j] = rrelu(acc);
        }
    }
#pragma unroll
    for (int j = 0; j < 4; ++j) {
#pragma unroll
        for (int k = 0; k < RPT; ++k) {
            float acc = bb[j];
#pragma unroll
            for (int i = 0; i < 4; ++i) acc = fmaf(t[k][i], Wb[i * 4 + j], acc);
            x[k][j] += acc;
        }
    }
}

__global__ __launch_bounds__(BLOCK) void ann_fused_kernel(
    const float* __restrict__ x_in, float* __restrict__ out, Weights w) {
    const int tid = blockIdx.x * BLOCK + threadIdx.x;
    const int T = N_ROWS / RPT;  // total threads; rows handled: tid + k*T

    // ---- load inputs: 2x float4 per row, coalesced per instruction ----
    float xin[RPT][8];
#pragma unroll
    for (int k = 0; k < RPT; ++k) {
        const float4* p =
            reinterpret_cast<const float4*>(x_in + (size_t)(tid + k * T) * 8);
        float4 a = p[0], b = p[1];
        xin[k][0] = a.x; xin[k][1] = a.y; xin[k][2] = a.z; xin[k][3] = a.w;
        xin[k][4] = b.x; xin[k][5] = b.y; xin[k][6] = b.z; xin[k][7] = b.w;
    }

    // ---- layer "in": 8->8, rrelu ----
    float t8[RPT][8];
#pragma unroll
    for (int j = 0; j < 8; ++j) {
#pragma unroll
        for (int k = 0; k < RPT; ++k) {
            float acc = w.b_in[j];
#pragma unroll
            for (int i = 0; i < 8; ++i) acc = fmaf(xin[k][i], w.W_in[i * 8 + j], acc);
            t8[k][j] = rrelu(acc);
        }
    }

    // ---- layer h1: 8->4, NO activation ----
    float x[RPT][4];
#pragma unroll
    for (int j = 0; j < 4; ++j) {
#pragma unroll
        for (int k = 0; k < RPT; ++k) {
            float acc = w.b_h1[j];
#pragma unroll
            for (int i = 0; i < 8; ++i) acc = fmaf(t8[k][i], w.W_h1[i * 4 + j], acc);
            x[k][j] = acc;
        }
    }

    resblock(x, w.W_h2, w.b_h2, w.W_h3, w.b_h3);
    resblock(x, w.W_h4, w.b_h4, w.W_h5, w.b_h5);

    // ---- encode: 4->1, rrelu ----
    float e[RPT];
#pragma unroll
    for (int k = 0; k < RPT; ++k) {
        float acc = w.b_enc[0];
#pragma unroll
        for (int i = 0; i < 4; ++i) acc = fmaf(x[k][i], w.W_enc[i], acc);
        e[k] = rrelu(acc);
    }

    // ---- h6: 1->4, rrelu ----
#pragma unroll
    for (int j = 0; j < 4; ++j) {
#pragma unroll
        for (int k = 0; k < RPT; ++k) {
            x[k][j] = rrelu(fmaf(e[k], w.W_h6[j], w.b_h6[j]));
        }
    }

    resblock(x, w.W_h7, w.b_h7, w.W_h8, w.b_h8);
    resblock(x, w.W_h9, w.b_h9, w.W_h10, w.b_h10);

    // ---- decode: 4->8, rrelu ----
    float d[RPT][8];
#pragma unroll
    for (int j = 0; j < 8; ++j) {
#pragma unroll
        for (int k = 0; k < RPT; ++k) {
            float acc = w.b_dec[j];
#pragma unroll
            for (int i = 0; i < 4; ++i) acc = fmaf(x[k][i], w.W_dec[i * 8 + j], acc);
            d[k][j] = rrelu(acc);
        }
    }

    // ---- stores: encode (1 dword/row, coalesced), decode (2x float4/row) ----
#pragma unroll
    for (int k = 0; k < RPT; ++k) {
        const int row = tid + k * T;
        out[row] = e[k];
        float4* q = reinterpret_cast<float4*>(out + N_ROWS + (size_t)row * 8);
        q[0] = make_float4(d[k][0], d[k][1], d[k][2], d[k][3]);
        q[1] = make_float4(d[k][4], d[k][5], d[k][6], d[k][7]);
    }
}

extern "C" void kernel_launch(void* const* d_in, const int* in_sizes, int n_in,
                              void* d_out, int out_size, void* d_ws, size_t ws_size,
                              hipStream_t stream) {
    const float* x_in = (const float*)d_in[0];
    Weights w;
    w.W_in  = (const float*)d_in[1];  w.b_in  = (const float*)d_in[2];
    w.W_h1  = (const float*)d_in[3];  w.b_h1  = (const float*)d_in[4];
    w.W_h2  = (const float*)d_in[5];  w.b_h2  = (const float*)d_in[6];
    w.W_h3  = (const float*)d_in[7];  w.b_h3  = (const float*)d_in[8];
    w.W_h4  = (const float*)d_in[9];  w.b_h4  = (const float*)d_in[10];
    w.W_h5  = (const float*)d_in[11]; w.b_h5  = (const float*)d_in[12];
    w.W_enc = (const float*)d_in[13]; w.b_enc = (const float*)d_in[14];
    w.W_h6  = (const float*)d_in[15]; w.b_h6  = (const float*)d_in[16];
    w.W_h7  = (const float*)d_in[17]; w.b_h7  = (const float*)d_in[18];
    w.W_h8  = (const float*)d_in[19]; w.b_h8  = (const float*)d_in[20];
    w.W_h9  = (const float*)d_in[21]; w.b_h9  = (const float*)d_in[22];
    w.W_h10 = (const float*)d_in[23]; w.b_h10 = (const float*)d_in[24];
    w.W_dec = (const float*)d_in[25]; w.b_dec = (const float*)d_in[26];
    float* out = (float*)d_out;

    const int total_threads = N_ROWS / RPT;
    dim3 grid(total_threads / BLOCK), block(BLOCK);
    ann_fused_kernel<<<grid, block, 0, stream>>>(x_in, out, w);
}